// Round 9
// baseline (175.690 us; speedup 1.0000x reference)
//
#include <hip/hip_runtime.h>
#include <hip/hip_bf16.h>
#include <stdint.h>

#define HEADS 8
#define DHEAD 64
#define BATCH 4
#define SEQ   8192
#define DIM   256
#define INNER 512
#define QKVC  1536
#define ROWS  32768   // BATCH*SEQ
#define EPS   1e-5f

typedef unsigned short u16;
typedef unsigned long long u64;
typedef __attribute__((ext_vector_type(8))) short bf16x8;
typedef __attribute__((ext_vector_type(4))) float f32x4;

#define AS1 __attribute__((address_space(1)))
#define AS3 __attribute__((address_space(3)))

__device__ __forceinline__ void async16(const void* g, void* l) {
  __builtin_amdgcn_global_load_lds((AS1 unsigned int*)g, (AS3 unsigned int*)l, 16, 0, 0);
}

__device__ __forceinline__ float bf2f(u16 u) {
  union { uint32_t i; float f; } v; v.i = ((uint32_t)u) << 16; return v.f;
}
__device__ __forceinline__ u16 f2bf(float f) {
  union { float f; uint32_t i; } v; v.f = f;
  uint32_t x = v.i;
  return (u16)((x + 0x7fffu + ((x >> 16) & 1u)) >> 16);  // RNE
}

// ---------------- prep ----------------
// blocks [0,8192): xb ; [8192,8704): wqB ; [8704,9728): wkvP (MFMA-fragment-packed)
// wkvP per head h (32768 u16): frag_id = ((kk*2+ks)*2+half)*4+fn  (64 frags);
//   elem(lane,j): kidx = kk*64+ks*32+(lane>>4)*8+j, col = half*64+fn*16+(lane&15),
//   oc = col<64 ? 512+h*64+col : 1024+h*64+(col-64); value = w[kidx][oc].
__global__ __launch_bounds__(256) void prep(const float* __restrict__ x,
                                            const float* __restrict__ w,
                                            u16* __restrict__ xb,
                                            u16* __restrict__ wqB,
                                            u16* __restrict__ wkvP) {
  int bid = blockIdx.x;
  if (bid < 8192) {
    int i = (bid * 256 + threadIdx.x) * 4;
    float4 v = *(const float4*)(x + i);
    ushort4 o; o.x = f2bf(v.x); o.y = f2bf(v.y); o.z = f2bf(v.z); o.w = f2bf(v.w);
    *(ushort4*)(xb + i) = o;
  } else if (bid < 8704) {
    int id = (bid - 8192) * 256 + threadIdx.x;  // 0..131071
    int k = id >> 9, j = id & 511;
    wqB[id] = f2bf(w[k * QKVC + j]);            // Wq row-major [256 k][512 j]
  } else {
    int id = (bid - 8704) * 256 + threadIdx.x;  // 0..262143
    int j    = id & 7;
    int lane = (id >> 3) & 63;
    int frag = (id >> 9) & 63;                  // 6 bits: 64 fragments
    int h    = id >> 15;                        // 3 bits: 8 heads
    int fn   = frag & 3;
    int half = (frag >> 2) & 1;
    int ks   = (frag >> 3) & 1;
    int kk   = frag >> 4;
    int col  = half * 64 + fn * 16 + (lane & 15);
    int kidx = kk * 64 + ks * 32 + (lane >> 4) * 8 + j;
    int oc   = (col < 64) ? (512 + h * 64 + col) : (1024 + h * 64 + (col - 64));
    wkvP[id] = f2bf(w[kidx * QKVC + oc]);
  }
}

// ---------------- shared GEMM tile core (C = A @ Bt^T), 128x128 tile, BK=64, 256 thr ----
// XOR-swizzled LDS: chunk c holds global chunk (row=c>>3, kc=(c^r)&7) ->
// b128 frag reads are bank-conflict-free; staging stays 128B-coalesced.
__device__ __forceinline__ void gemm_tile(const u16* __restrict__ A, int lda,
                                          const u16* __restrict__ Bt, int ldb,
                                          int K, int row0, int col0,
                                          u16* sA, u16* sB, f32x4 acc[4][4]) {
  const int tid = threadIdx.x, lane = tid & 63, wave = tid >> 6;
  const int m = lane & 15, q = lane >> 4;
  const int mr = (wave >> 1) * 64, nc = (wave & 1) * 64;
  for (int kk = 0; kk < K; kk += 64) {
#pragma unroll
    for (int it = 0; it < 4; ++it) {
      int c = it * 256 + tid;
      int r = c >> 3, kc = (c ^ r) & 7;
      async16(A + (size_t)(row0 + r) * lda + kk + kc * 8, sA + (it * 256 + wave * 64) * 8);
      async16(Bt + (size_t)(col0 + r) * ldb + kk + kc * 8, sB + (it * 256 + wave * 64) * 8);
    }
    __syncthreads();
#pragma unroll
    for (int ks = 0; ks < 2; ++ks) {
      bf16x8 af[4], bfr[4];
#pragma unroll
      for (int f = 0; f < 4; ++f) {
        int ra = mr + f * 16 + m;
        int rb = nc + f * 16 + m;
        af[f]  = *(const bf16x8*)&sA[ra * 64 + (((ks * 4 + q) ^ (m & 7)) * 8)];
        bfr[f] = *(const bf16x8*)&sB[rb * 64 + (((ks * 4 + q) ^ (m & 7)) * 8)];
      }
#pragma unroll
      for (int fm = 0; fm < 4; ++fm)
#pragma unroll
        for (int fn = 0; fn < 4; ++fn)
          acc[fm][fn] = __builtin_amdgcn_mfma_f32_16x16x32_bf16(af[fm], bfr[fn], acc[fm][fn], 0, 0, 0);
    }
    __syncthreads();
  }
}

// ---------------- GEMM-KV + instance norm + partial dots, BARRIER-FREE GEMM -----
// R8 post-mortem: R6/R7 head-sharing falsified the serial-chain theory (time
// invariant).  Root issue in R4: the A-tile has ZERO intra-block reuse — each
// (row, 8-elem chunk) feeds exactly one lane's af fragment (register-reused
// across fn).  LDS staging bought only coalescing and cost 8 barrier+vmcnt(0)
// drains per block.  R9: load af DIRECTLY from global (16 x 64B segments per
// load instr; L2-hot via the R0/R4-proven head-generation cadence, FETCH
// ~15MB), making the projection GEMM barrier-free: 64 indep loads + 128 MFMA
// per wave, freely scheduled.  LDS = knT/vnT only (34.8KB) -> 4 blocks/CU
// (16 waves) via launch_bounds(256,4).  ONE barrier per block (transpose).
__global__ __launch_bounds__(256, 4) void gemm_kv_dots(const u16* __restrict__ A,
                                                       const u16* __restrict__ wkvP,
                                                       u16* __restrict__ pdots) {
  __shared__ alignas(16) u16 smem[17408];  // 34816 B: knT/vnT transpose buffers
  u16* knT = smem;            // [64 d][136 tok]
  u16* vnT = smem + 8704;

  const int tid = threadIdx.x, lane = tid & 63, wave = tid >> 6;
  const int m = lane & 15, q = lane >> 4;
  const int row0 = blockIdx.x * 128;
  const int h = blockIdx.y;
  const int half = wave & 1;              // 0 = k cols, 1 = v cols
  const int rowbase = (wave >> 1) * 64;   // local token base of this wave's quadrant
  const u16* bp = wkvP + (size_t)h * 32768 + lane * 8;
  // af fragment base: row (row0+rowbase+f*16+m), col kk*64+(ks*4+q)*8
  const u16* ap = A + (size_t)(row0 + rowbase + m) * DIM + q * 8;

  f32x4 acc[4][4];
#pragma unroll
  for (int i = 0; i < 4; ++i)
#pragma unroll
    for (int j = 0; j < 4; ++j) acc[i][j] = (f32x4){0.f, 0.f, 0.f, 0.f};

#pragma unroll
  for (int kk = 0; kk < 4; ++kk) {
    bf16x8 breg[2][4];
#pragma unroll
    for (int ks = 0; ks < 2; ++ks)
#pragma unroll
      for (int fn = 0; fn < 4; ++fn)
        breg[ks][fn] = *(const bf16x8*)(bp + (size_t)((((kk * 2 + ks) * 2 + half) * 4 + fn) * 512));
#pragma unroll
    for (int ks = 0; ks < 2; ++ks) {
      bf16x8 af[4];
#pragma unroll
      for (int f = 0; f < 4; ++f)
        af[f] = *(const bf16x8*)(ap + f * 16 * DIM + kk * 64 + ks * 32);
#pragma unroll
      for (int fm = 0; fm < 4; ++fm)
#pragma unroll
        for (int fn = 0; fn < 4; ++fn)
          acc[fm][fn] = __builtin_amdgcn_mfma_f32_16x16x32_bf16(af[fm], breg[ks][fn], acc[fm][fn], 0, 0, 0);
    }
  }

  // epilogue: row stats via shfl butterfly over lane&15, write transposed bf16
  u16* dst = half ? vnT : knT;
#pragma unroll
  for (int fm = 0; fm < 4; ++fm) {
    f32x4 s  = acc[fm][0] + acc[fm][1] + acc[fm][2] + acc[fm][3];
    f32x4 s2 = (f32x4){0.f, 0.f, 0.f, 0.f};
#pragma unroll
    for (int fn = 0; fn < 4; ++fn)
#pragma unroll
      for (int r = 0; r < 4; ++r) s2[r] = fmaf(acc[fm][fn][r], acc[fm][fn][r], s2[r]);
#pragma unroll
    for (int mask = 1; mask <= 8; mask <<= 1) {
#pragma unroll
      for (int r = 0; r < 4; ++r) {
        s[r]  += __shfl_xor(s[r],  mask, 64);
        s2[r] += __shfl_xor(s2[r], mask, 64);
      }
    }
    f32x4 mu, rs;
#pragma unroll
    for (int r = 0; r < 4; ++r) {
      mu[r] = s[r] * (1.f / 64.f);
      float var = s2[r] * (1.f / 64.f) - mu[r] * mu[r];
      rs[r] = rsqrtf(var + EPS);
    }
    const int tokb = rowbase + fm * 16 + q * 4;
#pragma unroll
    for (int fn = 0; fn < 4; ++fn) {
      int d = fn * 16 + m;
      u64 pk = 0;
#pragma unroll
      for (int r = 0; r < 4; ++r) {
        u16 hv = f2bf((acc[fm][fn][r] - mu[r]) * rs[r]);
        pk |= (u64)hv << (16 * r);
      }
      *(u64*)(dst + d * 136 + tokb) = pk;   // 8B-aligned; 2-way bank alias (free)
    }
  }
  __syncthreads();   // the block's ONLY barrier: transpose visible to all waves

  // dacc[d][e] = sum_tok knT[d][tok]*vnT[e][tok] via MFMA (K=128 tokens)
  f32x4 dacc[4];
#pragma unroll
  for (int f = 0; f < 4; ++f) dacc[f] = (f32x4){0.f, 0.f, 0.f, 0.f};
#pragma unroll
  for (int ks = 0; ks < 4; ++ks) {
    bf16x8 a = *(const bf16x8*)&knT[(wave * 16 + m) * 136 + ks * 32 + q * 8];
#pragma unroll
    for (int fn = 0; fn < 4; ++fn) {
      bf16x8 bb = *(const bf16x8*)&vnT[(fn * 16 + m) * 136 + ks * 32 + q * 8];
      dacc[fn] = __builtin_amdgcn_mfma_f32_16x16x32_bf16(a, bb, dacc[fn], 0, 0, 0);
    }
  }

  // ONE streamed bf16 partial per block: pdots[(h*256+tile)][d][e]
  u16* pb = pdots + (size_t)(blockIdx.y * 256 + blockIdx.x) * 4096;
#pragma unroll
  for (int fn = 0; fn < 4; ++fn) {
    int e = fn * 16 + m;
#pragma unroll
    for (int r = 0; r < 4; ++r) {
      int d = wave * 16 + q * 4 + r;
      pb[d * 64 + e] = f2bf(dacc[fn][r]);
    }
  }
}

// ---------------- fold partial dots into w_out ----------------
// Mbt[b][c][h*64+j] = sum_e (sum_p pdots[h*256+b*64+p][j][e]) * w_out[h*64+e][c]/SEQ
__global__ __launch_bounds__(256) void make_M(const u16* __restrict__ pdots,
                                              const float* __restrict__ wout,
                                              u16* __restrict__ Mbt) {
  __shared__ float dl[8][64];
  const int bh = blockIdx.x, b = bh >> 3, h = bh & 7;
  const int jg = blockIdx.y;
  const int c = threadIdx.x;
  for (int i = threadIdx.x; i < 512; i += 256) {
    int jj = i >> 6, e = i & 63;
    const u16* src = pdots + (size_t)(h * 256 + b * 64) * 4096 + (jg * 8 + jj) * 64 + e;
    float sum = 0.f;
#pragma unroll 8
    for (int p = 0; p < 64; ++p) sum += bf2f(src[(size_t)p * 4096]);
    dl[jj][e] = sum;
  }
  __syncthreads();
  float accv[8];
#pragma unroll
  for (int jj = 0; jj < 8; ++jj) accv[jj] = 0.f;
  for (int e = 0; e < 64; ++e) {
    float w = wout[(h * 64 + e) * DIM + c];
#pragma unroll
    for (int jj = 0; jj < 8; ++jj) accv[jj] = fmaf(dl[jj][e], w, accv[jj]);
  }
  const float inv_n = 1.0f / (float)SEQ;
  u16* outp = Mbt + ((size_t)(b * 256 + c)) * 512 + h * 64 + jg * 8;
#pragma unroll
  for (int jj = 0; jj < 8; ++jj) outp[jj] = f2bf(accv[jj] * inv_n);
}

// ---------------- make_G: Gt[b][c][k] = sum_j Mbt[b][c][j] * wqB[k][j] ----------------
__global__ __launch_bounds__(256) void make_G(const u16* __restrict__ Mbt,
                                              const u16* __restrict__ wqB,
                                              u16* __restrict__ Gt) {
  __shared__ alignas(16) u16 sA[128 * 64];
  __shared__ alignas(16) u16 sB[128 * 64];
  const int lane = threadIdx.x & 63, wave = threadIdx.x >> 6;
  const int row0 = blockIdx.x * 128, col0 = blockIdx.y * 128;
  const int b = blockIdx.z;
  f32x4 acc[4][4];
#pragma unroll
  for (int i = 0; i < 4; ++i)
#pragma unroll
    for (int j = 0; j < 4; ++j) acc[i][j] = (f32x4){0.f, 0.f, 0.f, 0.f};

  gemm_tile(Mbt + (size_t)b * 256 * 512, INNER, wqB, INNER, INNER, row0, col0, sA, sB, acc);

  u16* out = Gt + (size_t)b * 256 * 256;
  const int mr = (wave >> 1) * 64, nc = (wave & 1) * 64;
#pragma unroll
  for (int fm = 0; fm < 4; ++fm) {
    int rbase = row0 + mr + fm * 16 + (lane >> 4) * 4;
#pragma unroll
    for (int fn = 0; fn < 4; ++fn) {
      int col = col0 + nc + fn * 16 + (lane & 15);
#pragma unroll
      for (int r = 0; r < 4; ++r)
        out[(size_t)(rbase + r) * DIM + col] = f2bf(acc[fm][fn][r]);
    }
  }
}

// ---------------- gemm_out: out = x @ G[b] + bias ; [32768,256]@[256,256] fp32 out ----
__global__ __launch_bounds__(256) void gemm_out(const u16* __restrict__ A,
                                                const u16* __restrict__ Gt,
                                                const float* __restrict__ bias,
                                                float* __restrict__ out) {
  __shared__ alignas(16) u16 sA[128 * 64];
  __shared__ alignas(16) u16 sB[128 * 64];
  const int lane = threadIdx.x & 63, wave = threadIdx.x >> 6;
  const int row0 = blockIdx.x * 128, col0 = blockIdx.y * 128;
  const int b = blockIdx.x >> 6;
  const u16* Bt = Gt + (size_t)b * 256 * 256;   // [256 cols][256 k]
  f32x4 acc[4][4];
#pragma unroll
  for (int i = 0; i < 4; ++i)
#pragma unroll
    for (int j = 0; j < 4; ++j) acc[i][j] = (f32x4){0.f, 0.f, 0.f, 0.f};

  gemm_tile(A, DIM, Bt, DIM, DIM, row0, col0, sA, sB, acc);

  const int mr = (wave >> 1) * 64, nc = (wave & 1) * 64;
#pragma unroll
  for (int fm = 0; fm < 4; ++fm) {
    int rbase = row0 + mr + fm * 16 + (lane >> 4) * 4;
#pragma unroll
    for (int fn = 0; fn < 4; ++fn) {
      int col = col0 + nc + fn * 16 + (lane & 15);
      float bb = bias[col];
#pragma unroll
      for (int r = 0; r < 4; ++r)
        out[(size_t)(rbase + r) * DIM + col] = acc[fm][fn][r] + bb;
    }
  }
}

// ---------------- launch ----------------
extern "C" void kernel_launch(void* const* d_in, const int* in_sizes, int n_in,
                              void* d_out, int out_size, void* d_ws, size_t ws_size,
                              hipStream_t stream) {
  const float* x     = (const float*)d_in[0];
  const float* w_qkv = (const float*)d_in[1];
  const float* w_out = (const float*)d_in[2];
  const float* b_out = (const float*)d_in[3];
  float* out = (float*)d_out;

  char* ws = (char*)d_ws;
  size_t off = 0;
  u16* xb    = (u16*)(ws + off); off += (size_t)ROWS * DIM * 2;          // 16.78 MB
  u16* wqB   = (u16*)(ws + off); off += (size_t)DIM * INNER * 2;         // 0.26 MB
  u16* wkvP  = (u16*)(ws + off); off += (size_t)HEADS * 128 * DIM * 2;   // 0.52 MB
  u16* Mbt   = (u16*)(ws + off); off += (size_t)BATCH * 256 * 512 * 2;   // 1.05 MB
  u16* Gt    = (u16*)(ws + off); off += (size_t)BATCH * 256 * 256 * 2;   // 0.52 MB
  // pdots scratch (16.78 MB) lives in the 33.55 MB output buffer: it is fully
  // consumed by make_M before gemm_out overwrites out.  Total ws: 19.13 MB.
  u16* pdots = (u16*)d_out;

  prep<<<9728, 256, 0, stream>>>(x, w_qkv, xb, wqB, wkvP);
  gemm_kv_dots<<<dim3(ROWS / 128, HEADS), 256, 0, stream>>>(xb, wkvP, pdots);
  make_M<<<dim3(32, 8), 256, 0, stream>>>(pdots, w_out, Mbt);
  make_G<<<dim3(2, 2, BATCH), 256, 0, stream>>>(Mbt, wqB, Gt);
  gemm_out<<<dim3(ROWS / 128, 2), 256, 0, stream>>>(xb, Gt, b_out, out);
}

// Round 10
// 175.390 us; speedup vs baseline: 1.0017x; 1.0017x over previous
//
#include <hip/hip_runtime.h>
#include <hip/hip_bf16.h>
#include <stdint.h>

#define HEADS 8
#define DHEAD 64
#define BATCH 4
#define SEQ   8192
#define DIM   256
#define INNER 512
#define QKVC  1536
#define ROWS  32768   // BATCH*SEQ
#define EPS   1e-5f

typedef unsigned short u16;
typedef unsigned long long u64;
typedef __attribute__((ext_vector_type(8))) short bf16x8;
typedef __attribute__((ext_vector_type(4))) float f32x4;

#define AS1 __attribute__((address_space(1)))
#define AS3 __attribute__((address_space(3)))

__device__ __forceinline__ void async16(const void* g, void* l) {
  __builtin_amdgcn_global_load_lds((AS1 unsigned int*)g, (AS3 unsigned int*)l, 16, 0, 0);
}

__device__ __forceinline__ float bf2f(u16 u) {
  union { uint32_t i; float f; } v; v.i = ((uint32_t)u) << 16; return v.f;
}
__device__ __forceinline__ u16 f2bf(float f) {
  union { float f; uint32_t i; } v; v.f = f;
  uint32_t x = v.i;
  return (u16)((x + 0x7fffu + ((x >> 16) & 1u)) >> 16);  // RNE
}

// ---------------- prep ----------------
// blocks [0,8192): xb ; [8192,8704): wqB ; [8704,9728): wkvP (MFMA-fragment-packed)
// wkvP per head h (32768 u16): frag_id = ((kk*2+ks)*2+half)*4+fn  (64 frags);
//   elem(lane,j): kidx = kk*64+ks*32+(lane>>4)*8+j, col = half*64+fn*16+(lane&15),
//   oc = col<64 ? 512+h*64+col : 1024+h*64+(col-64); value = w[kidx][oc].
__global__ __launch_bounds__(256) void prep(const float* __restrict__ x,
                                            const float* __restrict__ w,
                                            u16* __restrict__ xb,
                                            u16* __restrict__ wqB,
                                            u16* __restrict__ wkvP) {
  int bid = blockIdx.x;
  if (bid < 8192) {
    int i = (bid * 256 + threadIdx.x) * 4;
    float4 v = *(const float4*)(x + i);
    ushort4 o; o.x = f2bf(v.x); o.y = f2bf(v.y); o.z = f2bf(v.z); o.w = f2bf(v.w);
    *(ushort4*)(xb + i) = o;
  } else if (bid < 8704) {
    int id = (bid - 8192) * 256 + threadIdx.x;  // 0..131071
    int k = id >> 9, j = id & 511;
    wqB[id] = f2bf(w[k * QKVC + j]);            // Wq row-major [256 k][512 j]
  } else {
    int id = (bid - 8704) * 256 + threadIdx.x;  // 0..262143
    int j    = id & 7;
    int lane = (id >> 3) & 63;
    int frag = (id >> 9) & 63;                  // 6 bits: 64 fragments
    int h    = id >> 15;                        // 3 bits: 8 heads
    int fn   = frag & 3;
    int half = (frag >> 2) & 1;
    int ks   = (frag >> 3) & 1;
    int kk   = frag >> 4;
    int col  = half * 64 + fn * 16 + (lane & 15);
    int kidx = kk * 64 + ks * 32 + (lane >> 4) * 8 + j;
    int oc   = (col < 64) ? (512 + h * 64 + col) : (1024 + h * 64 + (col - 64));
    wkvP[id] = f2bf(w[kidx * QKVC + oc]);
  }
}

// ---------------- shared GEMM tile core (C = A @ Bt^T), 128x128 tile, BK=64, 256 thr ----
// XOR-swizzled LDS: chunk c holds global chunk (row=c>>3, kc=(c^r)&7) ->
// b128 frag reads are bank-conflict-free; staging stays 128B-coalesced.
__device__ __forceinline__ void gemm_tile(const u16* __restrict__ A, int lda,
                                          const u16* __restrict__ Bt, int ldb,
                                          int K, int row0, int col0,
                                          u16* sA, u16* sB, f32x4 acc[4][4]) {
  const int tid = threadIdx.x, lane = tid & 63, wave = tid >> 6;
  const int m = lane & 15, q = lane >> 4;
  const int mr = (wave >> 1) * 64, nc = (wave & 1) * 64;
  for (int kk = 0; kk < K; kk += 64) {
#pragma unroll
    for (int it = 0; it < 4; ++it) {
      int c = it * 256 + tid;
      int r = c >> 3, kc = (c ^ r) & 7;
      async16(A + (size_t)(row0 + r) * lda + kk + kc * 8, sA + (it * 256 + wave * 64) * 8);
      async16(Bt + (size_t)(col0 + r) * ldb + kk + kc * 8, sB + (it * 256 + wave * 64) * 8);
    }
    __syncthreads();
#pragma unroll
    for (int ks = 0; ks < 2; ++ks) {
      bf16x8 af[4], bfr[4];
#pragma unroll
      for (int f = 0; f < 4; ++f) {
        int ra = mr + f * 16 + m;
        int rb = nc + f * 16 + m;
        af[f]  = *(const bf16x8*)&sA[ra * 64 + (((ks * 4 + q) ^ (m & 7)) * 8)];
        bfr[f] = *(const bf16x8*)&sB[rb * 64 + (((ks * 4 + q) ^ (m & 7)) * 8)];
      }
#pragma unroll
      for (int fm = 0; fm < 4; ++fm)
#pragma unroll
        for (int fn = 0; fn < 4; ++fn)
          acc[fm][fn] = __builtin_amdgcn_mfma_f32_16x16x32_bf16(af[fm], bfr[fn], acc[fm][fn], 0, 0, 0);
    }
    __syncthreads();
  }
}

// ---------------- GEMM-KV + instance norm (register/shuffle) + partial dots ----------
// R9 post-mortem: direct-global af loads regressed 31.6->58.4us (segment-
// fragmented 64B reads on the MFMA dep chain; FETCH 15->26MB).  The LDS stage
// is latency BATCHING, not just coalescing — keep it.  This is the R4 champion
// structure (grid (256,8), 1 tile/block, stage->drain->MFMA, streamed bf16
// partial) with ONE change: launch_bounds(256,3) -> (256,4).  LDS 34816B x 4 =
// 139KB <= 160KB, so a 4th resident block/CU adds one more independent
// stage-drain latency stream per CU (the presumed limiter).
__global__ __launch_bounds__(256, 4) void gemm_kv_dots(const u16* __restrict__ A,
                                                       const u16* __restrict__ wkvP,
                                                       u16* __restrict__ pdots) {
  __shared__ alignas(16) u16 smem[17408];  // 34816 B
  u16* sA  = smem;            // [128 rows][64] swizzled, K-loop only
  u16* knT = smem;            // [64 d][136 tok] — aliases sA post K-loop
  u16* vnT = smem + 8704;

  const int tid = threadIdx.x, lane = tid & 63, wave = tid >> 6;
  const int m = lane & 15, q = lane >> 4;
  const int row0 = blockIdx.x * 128;
  const int h = blockIdx.y;
  const int half = wave & 1;              // 0 = k cols, 1 = v cols
  const int rowbase = (wave >> 1) * 64;   // local token base of this wave's quadrant
  const u16* bp = wkvP + (size_t)h * 32768 + lane * 8;

  f32x4 acc[4][4];
#pragma unroll
  for (int i = 0; i < 4; ++i)
#pragma unroll
    for (int j = 0; j < 4; ++j) acc[i][j] = (f32x4){0.f, 0.f, 0.f, 0.f};

#pragma unroll
  for (int kk = 0; kk < 4; ++kk) {
    // B fragments: coalesced 16B global loads, drained by the same barrier
    bf16x8 breg[2][4];
#pragma unroll
    for (int ks = 0; ks < 2; ++ks)
#pragma unroll
      for (int fn = 0; fn < 4; ++fn)
        breg[ks][fn] = *(const bf16x8*)(bp + (size_t)((((kk * 2 + ks) * 2 + half) * 4 + fn) * 512));
    // stage sA (swizzled)
#pragma unroll
    for (int it = 0; it < 4; ++it) {
      int c = it * 256 + tid;
      int r = c >> 3, kc = (c ^ r) & 7;
      async16(A + (size_t)(row0 + r) * DIM + kk * 64 + kc * 8, sA + (it * 256 + wave * 64) * 8);
    }
    __syncthreads();
#pragma unroll
    for (int ks = 0; ks < 2; ++ks) {
      bf16x8 af[4];
#pragma unroll
      for (int f = 0; f < 4; ++f) {
        int r = rowbase + f * 16 + m;
        af[f] = *(const bf16x8*)&sA[r * 64 + (((ks * 4 + q) ^ (m & 7)) * 8)];
      }
#pragma unroll
      for (int fm = 0; fm < 4; ++fm)
#pragma unroll
        for (int fn = 0; fn < 4; ++fn)
          acc[fm][fn] = __builtin_amdgcn_mfma_f32_16x16x32_bf16(af[fm], breg[ks][fn], acc[fm][fn], 0, 0, 0);
    }
    __syncthreads();
  }

  // epilogue: row stats via shfl butterfly over lane&15, write transposed bf16
  u16* dst = half ? vnT : knT;
#pragma unroll
  for (int fm = 0; fm < 4; ++fm) {
    f32x4 s  = acc[fm][0] + acc[fm][1] + acc[fm][2] + acc[fm][3];
    f32x4 s2 = (f32x4){0.f, 0.f, 0.f, 0.f};
#pragma unroll
    for (int fn = 0; fn < 4; ++fn)
#pragma unroll
      for (int r = 0; r < 4; ++r) s2[r] = fmaf(acc[fm][fn][r], acc[fm][fn][r], s2[r]);
#pragma unroll
    for (int mask = 1; mask <= 8; mask <<= 1) {
#pragma unroll
      for (int r = 0; r < 4; ++r) {
        s[r]  += __shfl_xor(s[r],  mask, 64);
        s2[r] += __shfl_xor(s2[r], mask, 64);
      }
    }
    f32x4 mu, rs;
#pragma unroll
    for (int r = 0; r < 4; ++r) {
      mu[r] = s[r] * (1.f / 64.f);
      float var = s2[r] * (1.f / 64.f) - mu[r] * mu[r];
      rs[r] = rsqrtf(var + EPS);
    }
    const int tokb = rowbase + fm * 16 + q * 4;
#pragma unroll
    for (int fn = 0; fn < 4; ++fn) {
      int d = fn * 16 + m;
      u64 pk = 0;
#pragma unroll
      for (int r = 0; r < 4; ++r) {
        u16 hv = f2bf((acc[fm][fn][r] - mu[r]) * rs[r]);
        pk |= (u64)hv << (16 * r);
      }
      *(u64*)(dst + d * 136 + tokb) = pk;   // 8B-aligned; 2-way bank alias (free)
    }
  }
  __syncthreads();

  // dacc[d][e] = sum_tok knT[d][tok]*vnT[e][tok] via MFMA (K=128 tokens)
  f32x4 dacc[4];
#pragma unroll
  for (int f = 0; f < 4; ++f) dacc[f] = (f32x4){0.f, 0.f, 0.f, 0.f};
#pragma unroll
  for (int ks = 0; ks < 4; ++ks) {
    bf16x8 a = *(const bf16x8*)&knT[(wave * 16 + m) * 136 + ks * 32 + q * 8];
#pragma unroll
    for (int fn = 0; fn < 4; ++fn) {
      bf16x8 bb = *(const bf16x8*)&vnT[(fn * 16 + m) * 136 + ks * 32 + q * 8];
      dacc[fn] = __builtin_amdgcn_mfma_f32_16x16x32_bf16(a, bb, dacc[fn], 0, 0, 0);
    }
  }

  // ONE streamed bf16 partial per block: pdots[(h*256+tile)][d][e]
  // rows [d][64 e] are exactly one 128B line; the wave's fn x r unrolled stores
  // complete each line so L2 write-combines to full-line HBM writes.
  u16* pb = pdots + (size_t)(blockIdx.y * 256 + blockIdx.x) * 4096;
#pragma unroll
  for (int fn = 0; fn < 4; ++fn) {
    int e = fn * 16 + m;
#pragma unroll
    for (int r = 0; r < 4; ++r) {
      int d = wave * 16 + q * 4 + r;
      pb[d * 64 + e] = f2bf(dacc[fn][r]);
    }
  }
}

// ---------------- fold partial dots into w_out ----------------
// Mbt[b][c][h*64+j] = sum_e (sum_p pdots[h*256+b*64+p][j][e]) * w_out[h*64+e][c]/SEQ
__global__ __launch_bounds__(256) void make_M(const u16* __restrict__ pdots,
                                              const float* __restrict__ wout,
                                              u16* __restrict__ Mbt) {
  __shared__ float dl[8][64];
  const int bh = blockIdx.x, b = bh >> 3, h = bh & 7;
  const int jg = blockIdx.y;
  const int c = threadIdx.x;
  for (int i = threadIdx.x; i < 512; i += 256) {
    int jj = i >> 6, e = i & 63;
    const u16* src = pdots + (size_t)(h * 256 + b * 64) * 4096 + (jg * 8 + jj) * 64 + e;
    float sum = 0.f;
#pragma unroll 8
    for (int p = 0; p < 64; ++p) sum += bf2f(src[(size_t)p * 4096]);
    dl[jj][e] = sum;
  }
  __syncthreads();
  float accv[8];
#pragma unroll
  for (int jj = 0; jj < 8; ++jj) accv[jj] = 0.f;
  for (int e = 0; e < 64; ++e) {
    float w = wout[(h * 64 + e) * DIM + c];
#pragma unroll
    for (int jj = 0; jj < 8; ++jj) accv[jj] = fmaf(dl[jj][e], w, accv[jj]);
  }
  const float inv_n = 1.0f / (float)SEQ;
  u16* outp = Mbt + ((size_t)(b * 256 + c)) * 512 + h * 64 + jg * 8;
#pragma unroll
  for (int jj = 0; jj < 8; ++jj) outp[jj] = f2bf(accv[jj] * inv_n);
}

// ---------------- make_G: Gt[b][c][k] = sum_j Mbt[b][c][j] * wqB[k][j] ----------------
__global__ __launch_bounds__(256) void make_G(const u16* __restrict__ Mbt,
                                              const u16* __restrict__ wqB,
                                              u16* __restrict__ Gt) {
  __shared__ alignas(16) u16 sA[128 * 64];
  __shared__ alignas(16) u16 sB[128 * 64];
  const int lane = threadIdx.x & 63, wave = threadIdx.x >> 6;
  const int row0 = blockIdx.x * 128, col0 = blockIdx.y * 128;
  const int b = blockIdx.z;
  f32x4 acc[4][4];
#pragma unroll
  for (int i = 0; i < 4; ++i)
#pragma unroll
    for (int j = 0; j < 4; ++j) acc[i][j] = (f32x4){0.f, 0.f, 0.f, 0.f};

  gemm_tile(Mbt + (size_t)b * 256 * 512, INNER, wqB, INNER, INNER, row0, col0, sA, sB, acc);

  u16* out = Gt + (size_t)b * 256 * 256;
  const int mr = (wave >> 1) * 64, nc = (wave & 1) * 64;
#pragma unroll
  for (int fm = 0; fm < 4; ++fm) {
    int rbase = row0 + mr + fm * 16 + (lane >> 4) * 4;
#pragma unroll
    for (int fn = 0; fn < 4; ++fn) {
      int col = col0 + nc + fn * 16 + (lane & 15);
#pragma unroll
      for (int r = 0; r < 4; ++r)
        out[(size_t)(rbase + r) * DIM + col] = f2bf(acc[fm][fn][r]);
    }
  }
}

// ---------------- gemm_out: out = x @ G[b] + bias ; [32768,256]@[256,256] fp32 out ----
__global__ __launch_bounds__(256) void gemm_out(const u16* __restrict__ A,
                                                const u16* __restrict__ Gt,
                                                const float* __restrict__ bias,
                                                float* __restrict__ out) {
  __shared__ alignas(16) u16 sA[128 * 64];
  __shared__ alignas(16) u16 sB[128 * 64];
  const int lane = threadIdx.x & 63, wave = threadIdx.x >> 6;
  const int row0 = blockIdx.x * 128, col0 = blockIdx.y * 128;
  const int b = blockIdx.x >> 6;
  const u16* Bt = Gt + (size_t)b * 256 * 256;   // [256 cols][256 k]
  f32x4 acc[4][4];
#pragma unroll
  for (int i = 0; i < 4; ++i)
#pragma unroll
    for (int j = 0; j < 4; ++j) acc[i][j] = (f32x4){0.f, 0.f, 0.f, 0.f};

  gemm_tile(A, DIM, Bt, DIM, DIM, row0, col0, sA, sB, acc);

  const int mr = (wave >> 1) * 64, nc = (wave & 1) * 64;
#pragma unroll
  for (int fm = 0; fm < 4; ++fm) {
    int rbase = row0 + mr + fm * 16 + (lane >> 4) * 4;
#pragma unroll
    for (int fn = 0; fn < 4; ++fn) {
      int col = col0 + nc + fn * 16 + (lane & 15);
      float bb = bias[col];
#pragma unroll
      for (int r = 0; r < 4; ++r)
        out[(size_t)(rbase + r) * DIM + col] = acc[fm][fn][r] + bb;
    }
  }
}

// ---------------- launch ----------------
extern "C" void kernel_launch(void* const* d_in, const int* in_sizes, int n_in,
                              void* d_out, int out_size, void* d_ws, size_t ws_size,
                              hipStream_t stream) {
  const float* x     = (const float*)d_in[0];
  const float* w_qkv = (const float*)d_in[1];
  const float* w_out = (const float*)d_in[2];
  const float* b_out = (const float*)d_in[3];
  float* out = (float*)d_out;

  char* ws = (char*)d_ws;
  size_t off = 0;
  u16* xb    = (u16*)(ws + off); off += (size_t)ROWS * DIM * 2;          // 16.78 MB
  u16* wqB   = (u16*)(ws + off); off += (size_t)DIM * INNER * 2;         // 0.26 MB
  u16* wkvP  = (u16*)(ws + off); off += (size_t)HEADS * 128 * DIM * 2;   // 0.52 MB
  u16* Mbt   = (u16*)(ws + off); off += (size_t)BATCH * 256 * 512 * 2;   // 1.05 MB
  u16* Gt    = (u16*)(ws + off); off += (size_t)BATCH * 256 * 256 * 2;   // 0.52 MB
  // pdots scratch (16.78 MB) lives in the 33.55 MB output buffer: it is fully
  // consumed by make_M before gemm_out overwrites out.  Total ws: 19.13 MB.
  u16* pdots = (u16*)d_out;

  prep<<<9728, 256, 0, stream>>>(x, w_qkv, xb, wqB, wkvP);
  gemm_kv_dots<<<dim3(ROWS / 128, HEADS), 256, 0, stream>>>(xb, wkvP, pdots);
  make_M<<<dim3(32, 8), 256, 0, stream>>>(pdots, w_out, Mbt);
  make_G<<<dim3(2, 2, BATCH), 256, 0, stream>>>(Mbt, wqB, Gt);
  gemm_out<<<dim3(ROWS / 128, 2), 256, 0, stream>>>(xb, Gt, b_out, out);
}

// Round 13
// 154.926 us; speedup vs baseline: 1.1340x; 1.1321x over previous
//
#include <hip/hip_runtime.h>
#include <hip/hip_bf16.h>
#include <stdint.h>

#define HEADS 8
#define DHEAD 64
#define BATCH 4
#define SEQ   8192
#define DIM   256
#define INNER 512
#define QKVC  1536
#define ROWS  32768   // BATCH*SEQ
#define EPS   1e-5f

typedef unsigned short u16;
typedef unsigned long long u64;
typedef __attribute__((ext_vector_type(8))) short bf16x8;
typedef __attribute__((ext_vector_type(4))) float f32x4;

#define AS1 __attribute__((address_space(1)))
#define AS3 __attribute__((address_space(3)))

__device__ __forceinline__ void async16(const void* g, void* l) {
  __builtin_amdgcn_global_load_lds((AS1 unsigned int*)g, (AS3 unsigned int*)l, 16, 0, 0);
}

__device__ __forceinline__ float bf2f(u16 u) {
  union { uint32_t i; float f; } v; v.i = ((uint32_t)u) << 16; return v.f;
}
__device__ __forceinline__ u16 f2bf(float f) {
  union { float f; uint32_t i; } v; v.f = f;
  uint32_t x = v.i;
  return (u16)((x + 0x7fffu + ((x >> 16) & 1u)) >> 16);  // RNE
}

// ---------------- prep ----------------
// blocks [0,8192): xb ; [8192,8704): wqB ; [8704,9728): wkvP (MFMA-fragment-packed)
// wkvP per head h (32768 u16): frag_id = ((kk*2+ks)*2+half)*4+fn  (64 frags);
//   elem(lane,j): kidx = kk*64+ks*32+(lane>>4)*8+j, col = half*64+fn*16+(lane&15),
//   oc = col<64 ? 512+h*64+col : 1024+h*64+(col-64); value = w[kidx][oc].
__global__ __launch_bounds__(256) void prep(const float* __restrict__ x,
                                            const float* __restrict__ w,
                                            u16* __restrict__ xb,
                                            u16* __restrict__ wqB,
                                            u16* __restrict__ wkvP) {
  int bid = blockIdx.x;
  if (bid < 8192) {
    int i = (bid * 256 + threadIdx.x) * 4;
    float4 v = *(const float4*)(x + i);
    ushort4 o; o.x = f2bf(v.x); o.y = f2bf(v.y); o.z = f2bf(v.z); o.w = f2bf(v.w);
    *(ushort4*)(xb + i) = o;
  } else if (bid < 8704) {
    int id = (bid - 8192) * 256 + threadIdx.x;  // 0..131071
    int k = id >> 9, j = id & 511;
    wqB[id] = f2bf(w[k * QKVC + j]);            // Wq row-major [256 k][512 j]
  } else {
    int id = (bid - 8704) * 256 + threadIdx.x;  // 0..262143
    int j    = id & 7;
    int lane = (id >> 3) & 63;
    int frag = (id >> 9) & 63;                  // 6 bits: 64 fragments
    int h    = id >> 15;                        // 3 bits: 8 heads
    int fn   = frag & 3;
    int half = (frag >> 2) & 1;
    int ks   = (frag >> 3) & 1;
    int kk   = frag >> 4;
    int col  = half * 64 + fn * 16 + (lane & 15);
    int kidx = kk * 64 + ks * 32 + (lane >> 4) * 8 + j;
    int oc   = (col < 64) ? (512 + h * 64 + col) : (1024 + h * 64 + (col - 64));
    wkvP[id] = f2bf(w[kidx * QKVC + oc]);
  }
}

// ---------------- shared GEMM tile core (C = A @ Bt^T), 128x128 tile, BK=64, 256 thr ----
// XOR-swizzled LDS: chunk c holds global chunk (row=c>>3, kc=(c^r)&7) ->
// b128 frag reads are bank-conflict-free; staging stays 128B-coalesced.
__device__ __forceinline__ void gemm_tile(const u16* __restrict__ A, int lda,
                                          const u16* __restrict__ Bt, int ldb,
                                          int K, int row0, int col0,
                                          u16* sA, u16* sB, f32x4 acc[4][4]) {
  const int tid = threadIdx.x, lane = tid & 63, wave = tid >> 6;
  const int m = lane & 15, q = lane >> 4;
  const int mr = (wave >> 1) * 64, nc = (wave & 1) * 64;
  for (int kk = 0; kk < K; kk += 64) {
#pragma unroll
    for (int it = 0; it < 4; ++it) {
      int c = it * 256 + tid;
      int r = c >> 3, kc = (c ^ r) & 7;
      async16(A + (size_t)(row0 + r) * lda + kk + kc * 8, sA + (it * 256 + wave * 64) * 8);
      async16(Bt + (size_t)(col0 + r) * ldb + kk + kc * 8, sB + (it * 256 + wave * 64) * 8);
    }
    __syncthreads();
#pragma unroll
    for (int ks = 0; ks < 2; ++ks) {
      bf16x8 af[4], bfr[4];
#pragma unroll
      for (int f = 0; f < 4; ++f) {
        int ra = mr + f * 16 + m;
        int rb = nc + f * 16 + m;
        af[f]  = *(const bf16x8*)&sA[ra * 64 + (((ks * 4 + q) ^ (m & 7)) * 8)];
        bfr[f] = *(const bf16x8*)&sB[rb * 64 + (((ks * 4 + q) ^ (m & 7)) * 8)];
      }
#pragma unroll
      for (int fm = 0; fm < 4; ++fm)
#pragma unroll
        for (int fn = 0; fn < 4; ++fn)
          acc[fm][fn] = __builtin_amdgcn_mfma_f32_16x16x32_bf16(af[fm], bfr[fn], acc[fm][fn], 0, 0, 0);
    }
    __syncthreads();
  }
}

// ---------------- GEMM-KV + instance norm (register/shuffle) + partial dots ----------
// CHAMPION (R4, 31.6us kv, 155.7 total) — byte-identical resubmit.
// Grid (256 tiles, 8 heads): flat bid = h*256+tile -> XCD = tile%8 pins all 8
// head-sharers of a tile to one XCD L2; at 3 blocks/CU the per-XCD tile working
// set fits the 4MB L2 -> FETCH ~15MB compulsory.  Bracketed: 2/CU slow (R6),
// 3/CU best (R4), 4/CU thrashes L2 (R10: FETCH 70MB).  R9: direct-global
// fragments regress (LDS stage = latency batching).  R5: kv dbuf neutral.
__global__ __launch_bounds__(256, 3) void gemm_kv_dots(const u16* __restrict__ A,
                                                       const u16* __restrict__ wkvP,
                                                       u16* __restrict__ pdots) {
  __shared__ alignas(16) u16 smem[17408];  // 34816 B
  u16* sA  = smem;            // [128 rows][64] swizzled, K-loop only
  u16* knT = smem;            // [64 d][136 tok] — aliases sA post K-loop
  u16* vnT = smem + 8704;

  const int tid = threadIdx.x, lane = tid & 63, wave = tid >> 6;
  const int m = lane & 15, q = lane >> 4;
  const int row0 = blockIdx.x * 128;
  const int h = blockIdx.y;
  const int half = wave & 1;              // 0 = k cols, 1 = v cols
  const int rowbase = (wave >> 1) * 64;   // local token base of this wave's quadrant
  const u16* bp = wkvP + (size_t)h * 32768 + lane * 8;

  f32x4 acc[4][4];
#pragma unroll
  for (int i = 0; i < 4; ++i)
#pragma unroll
    for (int j = 0; j < 4; ++j) acc[i][j] = (f32x4){0.f, 0.f, 0.f, 0.f};

#pragma unroll
  for (int kk = 0; kk < 4; ++kk) {
    // B fragments: coalesced 16B global loads, drained by the same barrier
    bf16x8 breg[2][4];
#pragma unroll
    for (int ks = 0; ks < 2; ++ks)
#pragma unroll
      for (int fn = 0; fn < 4; ++fn)
        breg[ks][fn] = *(const bf16x8*)(bp + (size_t)((((kk * 2 + ks) * 2 + half) * 4 + fn) * 512));
    // stage sA (swizzled)
#pragma unroll
    for (int it = 0; it < 4; ++it) {
      int c = it * 256 + tid;
      int r = c >> 3, kc = (c ^ r) & 7;
      async16(A + (size_t)(row0 + r) * DIM + kk * 64 + kc * 8, sA + (it * 256 + wave * 64) * 8);
    }
    __syncthreads();
#pragma unroll
    for (int ks = 0; ks < 2; ++ks) {
      bf16x8 af[4];
#pragma unroll
      for (int f = 0; f < 4; ++f) {
        int r = rowbase + f * 16 + m;
        af[f] = *(const bf16x8*)&sA[r * 64 + (((ks * 4 + q) ^ (m & 7)) * 8)];
      }
#pragma unroll
      for (int fm = 0; fm < 4; ++fm)
#pragma unroll
        for (int fn = 0; fn < 4; ++fn)
          acc[fm][fn] = __builtin_amdgcn_mfma_f32_16x16x32_bf16(af[fm], breg[ks][fn], acc[fm][fn], 0, 0, 0);
    }
    __syncthreads();
  }

  // epilogue: row stats via shfl butterfly over lane&15, write transposed bf16
  u16* dst = half ? vnT : knT;
#pragma unroll
  for (int fm = 0; fm < 4; ++fm) {
    f32x4 s  = acc[fm][0] + acc[fm][1] + acc[fm][2] + acc[fm][3];
    f32x4 s2 = (f32x4){0.f, 0.f, 0.f, 0.f};
#pragma unroll
    for (int fn = 0; fn < 4; ++fn)
#pragma unroll
      for (int r = 0; r < 4; ++r) s2[r] = fmaf(acc[fm][fn][r], acc[fm][fn][r], s2[r]);
#pragma unroll
    for (int mask = 1; mask <= 8; mask <<= 1) {
#pragma unroll
      for (int r = 0; r < 4; ++r) {
        s[r]  += __shfl_xor(s[r],  mask, 64);
        s2[r] += __shfl_xor(s2[r], mask, 64);
      }
    }
    f32x4 mu, rs;
#pragma unroll
    for (int r = 0; r < 4; ++r) {
      mu[r] = s[r] * (1.f / 64.f);
      float var = s2[r] * (1.f / 64.f) - mu[r] * mu[r];
      rs[r] = rsqrtf(var + EPS);
    }
    const int tokb = rowbase + fm * 16 + q * 4;
#pragma unroll
    for (int fn = 0; fn < 4; ++fn) {
      int d = fn * 16 + m;
      u64 pk = 0;
#pragma unroll
      for (int r = 0; r < 4; ++r) {
        u16 hv = f2bf((acc[fm][fn][r] - mu[r]) * rs[r]);
        pk |= (u64)hv << (16 * r);
      }
      *(u64*)(dst + d * 136 + tokb) = pk;   // 8B-aligned; 2-way bank alias (free)
    }
  }
  __syncthreads();

  // dacc[d][e] = sum_tok knT[d][tok]*vnT[e][tok] via MFMA (K=128 tokens)
  f32x4 dacc[4];
#pragma unroll
  for (int f = 0; f < 4; ++f) dacc[f] = (f32x4){0.f, 0.f, 0.f, 0.f};
#pragma unroll
  for (int ks = 0; ks < 4; ++ks) {
    bf16x8 a = *(const bf16x8*)&knT[(wave * 16 + m) * 136 + ks * 32 + q * 8];
#pragma unroll
    for (int fn = 0; fn < 4; ++fn) {
      bf16x8 bb = *(const bf16x8*)&vnT[(fn * 16 + m) * 136 + ks * 32 + q * 8];
      dacc[fn] = __builtin_amdgcn_mfma_f32_16x16x32_bf16(a, bb, dacc[fn], 0, 0, 0);
    }
  }

  // ONE streamed bf16 partial per block: pdots[(h*256+tile)][d][e]
  // rows [d][64 e] are exactly one 128B line; the wave's fn x r unrolled stores
  // complete each line so L2 write-combines to full-line HBM writes.
  u16* pb = pdots + (size_t)(blockIdx.y * 256 + blockIdx.x) * 4096;
#pragma unroll
  for (int fn = 0; fn < 4; ++fn) {
    int e = fn * 16 + m;
#pragma unroll
    for (int r = 0; r < 4; ++r) {
      int d = wave * 16 + q * 4 + r;
      pb[d * 64 + e] = f2bf(dacc[fn][r]);
    }
  }
}

// ---------------- fold partial dots into w_out ----------------
// Mbt[b][c][h*64+j] = sum_e (sum_p pdots[h*256+b*64+p][j][e]) * w_out[h*64+e][c]/SEQ
__global__ __launch_bounds__(256) void make_M(const u16* __restrict__ pdots,
                                              const float* __restrict__ wout,
                                              u16* __restrict__ Mbt) {
  __shared__ float dl[8][64];
  const int bh = blockIdx.x, b = bh >> 3, h = bh & 7;
  const int jg = blockIdx.y;
  const int c = threadIdx.x;
  for (int i = threadIdx.x; i < 512; i += 256) {
    int jj = i >> 6, e = i & 63;
    const u16* src = pdots + (size_t)(h * 256 + b * 64) * 4096 + (jg * 8 + jj) * 64 + e;
    float sum = 0.f;
#pragma unroll 8
    for (int p = 0; p < 64; ++p) sum += bf2f(src[(size_t)p * 4096]);
    dl[jj][e] = sum;
  }
  __syncthreads();
  float accv[8];
#pragma unroll
  for (int jj = 0; jj < 8; ++jj) accv[jj] = 0.f;
  for (int e = 0; e < 64; ++e) {
    float w = wout[(h * 64 + e) * DIM + c];
#pragma unroll
    for (int jj = 0; jj < 8; ++jj) accv[jj] = fmaf(dl[jj][e], w, accv[jj]);
  }
  const float inv_n = 1.0f / (float)SEQ;
  u16* outp = Mbt + ((size_t)(b * 256 + c)) * 512 + h * 64 + jg * 8;
#pragma unroll
  for (int jj = 0; jj < 8; ++jj) outp[jj] = f2bf(accv[jj] * inv_n);
}

// ---------------- make_G: Gt[b][c][k] = sum_j Mbt[b][c][j] * wqB[k][j] ----------------
__global__ __launch_bounds__(256) void make_G(const u16* __restrict__ Mbt,
                                              const u16* __restrict__ wqB,
                                              u16* __restrict__ Gt) {
  __shared__ alignas(16) u16 sA[128 * 64];
  __shared__ alignas(16) u16 sB[128 * 64];
  const int lane = threadIdx.x & 63, wave = threadIdx.x >> 6;
  const int row0 = blockIdx.x * 128, col0 = blockIdx.y * 128;
  const int b = blockIdx.z;
  f32x4 acc[4][4];
#pragma unroll
  for (int i = 0; i < 4; ++i)
#pragma unroll
    for (int j = 0; j < 4; ++j) acc[i][j] = (f32x4){0.f, 0.f, 0.f, 0.f};

  gemm_tile(Mbt + (size_t)b * 256 * 512, INNER, wqB, INNER, INNER, row0, col0, sA, sB, acc);

  u16* out = Gt + (size_t)b * 256 * 256;
  const int mr = (wave >> 1) * 64, nc = (wave & 1) * 64;
#pragma unroll
  for (int fm = 0; fm < 4; ++fm) {
    int rbase = row0 + mr + fm * 16 + (lane >> 4) * 4;
#pragma unroll
    for (int fn = 0; fn < 4; ++fn) {
      int col = col0 + nc + fn * 16 + (lane & 15);
#pragma unroll
      for (int r = 0; r < 4; ++r)
        out[(size_t)(rbase + r) * DIM + col] = f2bf(acc[fm][fn][r]);
    }
  }
}

// ---------------- gemm_out: out = x @ G[b] + bias ; [32768,256]@[256,256] fp32 out ----
__global__ __launch_bounds__(256) void gemm_out(const u16* __restrict__ A,
                                                const u16* __restrict__ Gt,
                                                const float* __restrict__ bias,
                                                float* __restrict__ out) {
  __shared__ alignas(16) u16 sA[128 * 64];
  __shared__ alignas(16) u16 sB[128 * 64];
  const int lane = threadIdx.x & 63, wave = threadIdx.x >> 6;
  const int row0 = blockIdx.x * 128, col0 = blockIdx.y * 128;
  const int b = blockIdx.x >> 6;
  const u16* Bt = Gt + (size_t)b * 256 * 256;   // [256 cols][256 k]
  f32x4 acc[4][4];
#pragma unroll
  for (int i = 0; i < 4; ++i)
#pragma unroll
    for (int j = 0; j < 4; ++j) acc[i][j] = (f32x4){0.f, 0.f, 0.f, 0.f};

  gemm_tile(A, DIM, Bt, DIM, DIM, row0, col0, sA, sB, acc);

  const int mr = (wave >> 1) * 64, nc = (wave & 1) * 64;
#pragma unroll
  for (int fm = 0; fm < 4; ++fm) {
    int rbase = row0 + mr + fm * 16 + (lane >> 4) * 4;
#pragma unroll
    for (int fn = 0; fn < 4; ++fn) {
      int col = col0 + nc + fn * 16 + (lane & 15);
      float bb = bias[col];
#pragma unroll
      for (int r = 0; r < 4; ++r)
        out[(size_t)(rbase + r) * DIM + col] = acc[fm][fn][r] + bb;
    }
  }
}

// ---------------- launch ----------------
extern "C" void kernel_launch(void* const* d_in, const int* in_sizes, int n_in,
                              void* d_out, int out_size, void* d_ws, size_t ws_size,
                              hipStream_t stream) {
  const float* x     = (const float*)d_in[0];
  const float* w_qkv = (const float*)d_in[1];
  const float* w_out = (const float*)d_in[2];
  const float* b_out = (const float*)d_in[3];
  float* out = (float*)d_out;

  char* ws = (char*)d_ws;
  size_t off = 0;
  u16* xb    = (u16*)(ws + off); off += (size_t)ROWS * DIM * 2;          // 16.78 MB
  u16* wqB   = (u16*)(ws + off); off += (size_t)DIM * INNER * 2;         // 0.26 MB
  u16* wkvP  = (u16*)(ws + off); off += (size_t)HEADS * 128 * DIM * 2;   // 0.52 MB
  u16* Mbt   = (u16*)(ws + off); off += (size_t)BATCH * 256 * 512 * 2;   // 1.05 MB
  u16* Gt    = (u16*)(ws + off); off += (size_t)BATCH * 256 * 256 * 2;   // 0.52 MB
  // pdots scratch (16.78 MB) lives in the 33.55 MB output buffer: it is fully
  // consumed by make_M before gemm_out overwrites out.  Total ws: 19.13 MB.
  u16* pdots = (u16*)d_out;

  prep<<<9728, 256, 0, stream>>>(x, w_qkv, xb, wqB, wkvP);
  gemm_kv_dots<<<dim3(ROWS / 128, HEADS), 256, 0, stream>>>(xb, wkvP, pdots);
  make_M<<<dim3(32, 8), 256, 0, stream>>>(pdots, w_out, Mbt);
  make_G<<<dim3(2, 2, BATCH), 256, 0, stream>>>(Mbt, wqB, Gt);
  gemm_out<<<dim3(ROWS / 128, 2), 256, 0, stream>>>(xb, Gt, b_out, out);
}